// Round 2
// baseline (445.445 us; speedup 1.0000x reference)
//
#include <hip/hip_runtime.h>
#include <hip/hip_bf16.h>
#include <cstdint>

// ---------------- CSR build ----------------

__global__ __launch_bounds__(256) void zero_kernel(int* __restrict__ p, int n) {
    int i = blockIdx.x * 256 + threadIdx.x;
    if (i < n) p[i] = 0;
}

__global__ __launch_bounds__(256) void count_kernel(const int* __restrict__ dst, int E,
                                                    int* __restrict__ cnt, int n) {
    int e = blockIdx.x * 256 + threadIdx.x;
    if (e < E) {
        int d = dst[e];
        if (d >= 0 && d < n) atomicAdd(&cnt[d], 1);
    }
}

__global__ __launch_bounds__(1024) void scan_kernel(const int* __restrict__ cnt, int n,
                                                    int* __restrict__ offsets, int* __restrict__ cursor,
                                                    float* __restrict__ dinv) {
    __shared__ int part[1024];
    const int t = threadIdx.x;
    const int chunk = (n + 1023) >> 10;
    const int lo = min(t * chunk, n);
    const int hi = min(lo + chunk, n);
    int sum = 0;
    for (int i = lo; i < hi; ++i) sum += cnt[i];
    part[t] = sum;
    __syncthreads();
    // Hillis-Steele inclusive scan over 1024 partials
    for (int off = 1; off < 1024; off <<= 1) {
        int val = (t >= off) ? part[t - off] : 0;
        __syncthreads();
        part[t] += val;
        __syncthreads();
    }
    int base = (t == 0) ? 0 : part[t - 1];
    for (int i = lo; i < hi; ++i) {
        offsets[i] = base;
        cursor[i] = base;
        int c = cnt[i];
        dinv[i] = rsqrtf((float)(c + 1));  // +1 self-loop; deg >= 1 always
        base += c;
    }
    if (t == 0) offsets[n] = part[1023];
}

__global__ __launch_bounds__(256) void fill_kernel(const int* __restrict__ src,
                                                   const int* __restrict__ dst, int E,
                                                   int* __restrict__ cursor, int* __restrict__ csr,
                                                   int n) {
    int e = blockIdx.x * 256 + threadIdx.x;
    if (e < E) {
        int d = dst[e];
        int s = src[e];
        if (d >= 0 && d < n && s >= 0 && s < n) {
            int pos = atomicAdd(&cursor[d], 1);
            csr[pos] = s;
        }
    }
}

// ---------------- GEMM with dinv-scale epilogue: G = diag(dinv) * (X @ W) ----------------

template<int DIN, int DOUT, int ROWS>
__global__ __launch_bounds__(256) void gemm_scale_kernel(const float* __restrict__ X,
                                                         const float* __restrict__ W,
                                                         const float* __restrict__ dinv,
                                                         float* __restrict__ G, int n) {
    constexpr int CG  = DOUT / 4;     // col groups (each thread does 4 cols)
    constexpr int RG  = 256 / CG;     // row groups
    constexpr int RPT = ROWS / RG;    // rows per thread
    constexpr int PAD = (DIN * DOUT * 4 > 32768) ? 0 : 4;
    constexpr int XS  = DIN + PAD;
    __shared__ float Ws[DIN * DOUT];
    __shared__ float Xs[ROWS * XS];
    const int t = threadIdx.x;
    const int row0 = blockIdx.x * ROWS;

    for (int i = t * 4; i < DIN * DOUT; i += 256 * 4)
        *reinterpret_cast<float4*>(&Ws[i]) = *reinterpret_cast<const float4*>(&W[i]);
    for (int i = t * 4; i < ROWS * DIN; i += 256 * 4) {
        int r = i / DIN, k = i % DIN;
        float4 v = make_float4(0.f, 0.f, 0.f, 0.f);
        if (row0 + r < n) v = *reinterpret_cast<const float4*>(&X[(size_t)(row0 + r) * DIN + k]);
        *reinterpret_cast<float4*>(&Xs[r * XS + k]) = v;
    }
    __syncthreads();

    const int tx = t % CG, ty = t / CG;
    float acc[RPT][4];
#pragma unroll
    for (int rr = 0; rr < RPT; ++rr) {
        acc[rr][0] = 0.f; acc[rr][1] = 0.f; acc[rr][2] = 0.f; acc[rr][3] = 0.f;
    }

#pragma unroll 4
    for (int k = 0; k < DIN; ++k) {
        float4 w = *reinterpret_cast<const float4*>(&Ws[k * DOUT + tx * 4]);
#pragma unroll
        for (int rr = 0; rr < RPT; ++rr) {
            float xv = Xs[(ty * RPT + rr) * XS + k];
            acc[rr][0] += xv * w.x;
            acc[rr][1] += xv * w.y;
            acc[rr][2] += xv * w.z;
            acc[rr][3] += xv * w.w;
        }
    }

#pragma unroll
    for (int rr = 0; rr < RPT; ++rr) {
        int r = row0 + ty * RPT + rr;
        if (r < n) {
            float s = dinv[r];
            float4 o = make_float4(acc[rr][0] * s, acc[rr][1] * s, acc[rr][2] * s, acc[rr][3] * s);
            *reinterpret_cast<float4*>(&G[(size_t)r * DOUT + tx * 4]) = o;
        }
    }
}

// ---------------- Aggregate: out[v] = act( dinv[v] * (g[v] + sum_{u in adj(v)} g[u]) + b ) ----------------

template<int D, bool RELU>
__global__ __launch_bounds__(256) void aggregate_kernel(const float* __restrict__ G,
                                                        const int* __restrict__ offsets,
                                                        const int* __restrict__ csr,
                                                        const float* __restrict__ dinv,
                                                        const float* __restrict__ bias,
                                                        float* __restrict__ out, int n) {
    constexpr int LPN = (D >= 64) ? 64 : D;  // lanes per node
    constexpr int VEC = D / LPN;             // 2 for D=128, else 1
    constexpr int NPW = 64 / LPN;            // nodes per wave
    const int lane = threadIdx.x & 63;
    const int wave = (int)((blockIdx.x * 256 + threadIdx.x) >> 6);
    const int v = wave * NPW + lane / LPN;
    if (v >= n) return;
    const int col = (lane % LPN) * VEC;
    const float* gB = G + col;

    float a0, a1 = 0.f, c0 = 0.f, c1 = 0.f;
    if (VEC == 2) {
        float2 sv = *reinterpret_cast<const float2*>(&gB[(size_t)v * D]);
        a0 = sv.x; a1 = sv.y;
    } else {
        a0 = gB[(size_t)v * D];
    }

    const int s = offsets[v], e = offsets[v + 1];
    int j = s;
    for (; j + 2 <= e; j += 2) {
        int u0 = csr[j], u1 = csr[j + 1];
        if (VEC == 2) {
            float2 x0 = *reinterpret_cast<const float2*>(&gB[(size_t)u0 * D]);
            float2 x1 = *reinterpret_cast<const float2*>(&gB[(size_t)u1 * D]);
            a0 += x0.x; a1 += x0.y;
            c0 += x1.x; c1 += x1.y;
        } else {
            float x0 = gB[(size_t)u0 * D];
            float x1 = gB[(size_t)u1 * D];
            a0 += x0; c0 += x1;
        }
    }
    if (j < e) {
        int u = csr[j];
        if (VEC == 2) {
            float2 x = *reinterpret_cast<const float2*>(&gB[(size_t)u * D]);
            a0 += x.x; a1 += x.y;
        } else {
            a0 += gB[(size_t)u * D];
        }
    }
    a0 += c0; a1 += c1;

    const float dv = dinv[v];
    float o0 = dv * a0 + bias[col];
    if (RELU) o0 = fmaxf(o0, 0.f);
    if (VEC == 2) {
        float o1 = dv * a1 + bias[col + 1];
        if (RELU) o1 = fmaxf(o1, 0.f);
        *reinterpret_cast<float2*>(&out[(size_t)v * D + col]) = make_float2(o0, o1);
    } else {
        out[(size_t)v * D + col] = o0;
    }
}

// ---------------- launch ----------------

extern "C" void kernel_launch(void* const* d_in, const int* in_sizes, int n_in,
                              void* d_out, int out_size, void* d_ws, size_t ws_size,
                              hipStream_t stream) {
    const int N = 50000, E = 800000;
    const float* x  = (const float*)d_in[0];
    const int* ei = (const int*)d_in[1];   // harness converts int64 -> int32
    const int* src = ei;
    const int* dst = ei + E;
    const float* W1 = (const float*)d_in[2]; const float* b1 = (const float*)d_in[3];
    const float* W2 = (const float*)d_in[4]; const float* b2 = (const float*)d_in[5];
    const float* W3 = (const float*)d_in[6]; const float* b3 = (const float*)d_in[7];
    float* out = (float*)d_out;

    char* ws = (char*)d_ws;
    size_t off = 0;
    auto alloc = [&](size_t bytes) -> void* {
        void* p = ws + off;
        off = (off + bytes + 255) & ~(size_t)255;
        return p;
    };
    int*   cnt     = (int*)alloc((size_t)N * 4);
    int*   offsets = (int*)alloc((size_t)(N + 1) * 4);
    int*   cursor  = (int*)alloc((size_t)N * 4);
    float* dinv    = (float*)alloc((size_t)N * 4);
    int*   csr     = (int*)alloc((size_t)E * 4);
    float* g       = (float*)alloc((size_t)N * 128 * 4);
    float* h       = (float*)alloc((size_t)N * 128 * 4);
    (void)ws_size; (void)n_in; (void)in_sizes; (void)out_size;

    // CSR build (dst-keyed; stores src)
    zero_kernel<<<(N + 255) / 256, 256, 0, stream>>>(cnt, N);
    count_kernel<<<(E + 255) / 256, 256, 0, stream>>>(dst, E, cnt, N);
    scan_kernel<<<1, 1024, 0, stream>>>(cnt, N, offsets, cursor, dinv);
    fill_kernel<<<(E + 255) / 256, 256, 0, stream>>>(src, dst, E, cursor, csr, N);

    // layer 1: 128 -> 128, relu
    gemm_scale_kernel<128, 128, 32><<<(N + 31) / 32, 256, 0, stream>>>(x, W1, dinv, g, N);
    aggregate_kernel<128, true><<<(N + 3) / 4, 256, 0, stream>>>(g, offsets, csr, dinv, b1, h, N);
    // layer 2: 128 -> 64, relu
    gemm_scale_kernel<128, 64, 32><<<(N + 31) / 32, 256, 0, stream>>>(h, W2, dinv, g, N);
    aggregate_kernel<64, true><<<(N + 3) / 4, 256, 0, stream>>>(g, offsets, csr, dinv, b2, h, N);
    // layer 3: 64 -> 32, no relu -> d_out
    gemm_scale_kernel<64, 32, 32><<<(N + 31) / 32, 256, 0, stream>>>(h, W3, dinv, g, N);
    aggregate_kernel<32, false><<<(N + 7) / 8, 256, 0, stream>>>(g, offsets, csr, dinv, b3, out, N);
}

// Round 3
// 321.731 us; speedup vs baseline: 1.3845x; 1.3845x over previous
//
#include <hip/hip_runtime.h>
#include <hip/hip_bf16.h>
#include <cstdint>

// ---------------- CSR build ----------------

__global__ __launch_bounds__(256) void zero_kernel(int* __restrict__ p, int n) {
    int i = blockIdx.x * 256 + threadIdx.x;
    if (i < n) p[i] = 0;
}

__global__ __launch_bounds__(256) void count_kernel(const int* __restrict__ dst, int E,
                                                    int* __restrict__ cnt, int n) {
    int e = blockIdx.x * 256 + threadIdx.x;
    if (e < E) {
        int d = dst[e];
        if (d >= 0 && d < n) atomicAdd(&cnt[d], 1);
    }
}

// two-level scan: (A) per-block sums, (B) scan partials, (C) write offsets
__global__ __launch_bounds__(256) void block_reduce_kernel(const int* __restrict__ cnt, int n,
                                                           int* __restrict__ bsum) {
    __shared__ int sh[256];
    const int t = threadIdx.x;
    const int i = blockIdx.x * 256 + t;
    sh[t] = (i < n) ? cnt[i] : 0;
    __syncthreads();
    for (int off = 128; off > 0; off >>= 1) {
        if (t < off) sh[t] += sh[t + off];
        __syncthreads();
    }
    if (t == 0) bsum[blockIdx.x] = sh[0];
}

__global__ __launch_bounds__(256) void scan_partials_kernel(const int* __restrict__ bsum, int nb,
                                                            int* __restrict__ bbase,
                                                            int* __restrict__ total_out) {
    __shared__ int sh[256];
    const int t = threadIdx.x;
    const int v = (t < nb) ? bsum[t] : 0;
    sh[t] = v;
    __syncthreads();
    for (int off = 1; off < 256; off <<= 1) {
        int val = (t >= off) ? sh[t - off] : 0;
        __syncthreads();
        sh[t] += val;
        __syncthreads();
    }
    bbase[t] = sh[t] - v;                    // exclusive base for block t
    if (t == nb - 1) total_out[0] = sh[t];   // offsets[n]
}

__global__ __launch_bounds__(256) void write_offsets_kernel(const int* __restrict__ cnt, int n,
                                                            const int* __restrict__ bbase,
                                                            int* __restrict__ offsets,
                                                            int* __restrict__ cursor,
                                                            float* __restrict__ dinv) {
    __shared__ int sh[256];
    const int t = threadIdx.x;
    const int i = blockIdx.x * 256 + t;
    const int c = (i < n) ? cnt[i] : 0;
    sh[t] = c;
    __syncthreads();
    for (int off = 1; off < 256; off <<= 1) {
        int val = (t >= off) ? sh[t - off] : 0;
        __syncthreads();
        sh[t] += val;
        __syncthreads();
    }
    if (i < n) {
        int excl = sh[t] - c + bbase[blockIdx.x];
        offsets[i] = excl;
        cursor[i] = excl;
        dinv[i] = rsqrtf((float)(c + 1));  // +1 self-loop; deg >= 1 always
    }
}

__global__ __launch_bounds__(256) void fill_kernel(const int* __restrict__ src,
                                                   const int* __restrict__ dst, int E,
                                                   int* __restrict__ cursor, int* __restrict__ csr,
                                                   int n) {
    int e = blockIdx.x * 256 + threadIdx.x;
    if (e < E) {
        int d = dst[e];
        int s = src[e];
        if (d >= 0 && d < n && s >= 0 && s < n) {
            int pos = atomicAdd(&cursor[d], 1);
            csr[pos] = s;
        }
    }
}

// ---------------- GEMM with dinv-scale epilogue: G = diag(dinv) * (X @ W) ----------------

template<int DIN, int DOUT, int ROWS>
__global__ __launch_bounds__(256) void gemm_scale_kernel(const float* __restrict__ X,
                                                         const float* __restrict__ W,
                                                         const float* __restrict__ dinv,
                                                         float* __restrict__ G, int n) {
    constexpr int CG  = DOUT / 4;     // col groups (each thread does 4 cols)
    constexpr int RG  = 256 / CG;     // row groups
    constexpr int RPT = ROWS / RG;    // rows per thread
    constexpr int PAD = (DIN * DOUT * 4 > 32768) ? 0 : 4;
    constexpr int XS  = DIN + PAD;
    __shared__ float Ws[DIN * DOUT];
    __shared__ float Xs[ROWS * XS];
    const int t = threadIdx.x;
    const int row0 = blockIdx.x * ROWS;

    for (int i = t * 4; i < DIN * DOUT; i += 256 * 4)
        *reinterpret_cast<float4*>(&Ws[i]) = *reinterpret_cast<const float4*>(&W[i]);
    for (int i = t * 4; i < ROWS * DIN; i += 256 * 4) {
        int r = i / DIN, k = i % DIN;
        float4 v = make_float4(0.f, 0.f, 0.f, 0.f);
        if (row0 + r < n) v = *reinterpret_cast<const float4*>(&X[(size_t)(row0 + r) * DIN + k]);
        *reinterpret_cast<float4*>(&Xs[r * XS + k]) = v;
    }
    __syncthreads();

    const int tx = t % CG, ty = t / CG;
    float acc[RPT][4];
#pragma unroll
    for (int rr = 0; rr < RPT; ++rr) {
        acc[rr][0] = 0.f; acc[rr][1] = 0.f; acc[rr][2] = 0.f; acc[rr][3] = 0.f;
    }

#pragma unroll 4
    for (int k = 0; k < DIN; ++k) {
        float4 w = *reinterpret_cast<const float4*>(&Ws[k * DOUT + tx * 4]);
#pragma unroll
        for (int rr = 0; rr < RPT; ++rr) {
            float xv = Xs[(ty * RPT + rr) * XS + k];
            acc[rr][0] += xv * w.x;
            acc[rr][1] += xv * w.y;
            acc[rr][2] += xv * w.z;
            acc[rr][3] += xv * w.w;
        }
    }

#pragma unroll
    for (int rr = 0; rr < RPT; ++rr) {
        int r = row0 + ty * RPT + rr;
        if (r < n) {
            float s = dinv[r];
            float4 o = make_float4(acc[rr][0] * s, acc[rr][1] * s, acc[rr][2] * s, acc[rr][3] * s);
            *reinterpret_cast<float4*>(&G[(size_t)r * DOUT + tx * 4]) = o;
        }
    }
}

// ---------------- Aggregate: out[v] = act( dinv[v] * (g[v] + sum_{u in adj(v)} g[u]) + b ) ----------------

template<int D, bool RELU>
__global__ __launch_bounds__(256) void aggregate_kernel(const float* __restrict__ G,
                                                        const int* __restrict__ offsets,
                                                        const int* __restrict__ csr,
                                                        const float* __restrict__ dinv,
                                                        const float* __restrict__ bias,
                                                        float* __restrict__ out, int n) {
    constexpr int LPN = (D >= 64) ? 64 : D;  // lanes per node
    constexpr int VEC = D / LPN;             // 2 for D=128, else 1
    constexpr int NPW = 64 / LPN;            // nodes per wave
    const int lane = threadIdx.x & 63;
    const int wave = (int)((blockIdx.x * 256 + threadIdx.x) >> 6);
    const int v = wave * NPW + lane / LPN;
    if (v >= n) return;
    const int col = (lane % LPN) * VEC;
    const float* gB = G + col;

    float a0, a1 = 0.f, c0 = 0.f, c1 = 0.f;
    if (VEC == 2) {
        float2 sv = *reinterpret_cast<const float2*>(&gB[(size_t)v * D]);
        a0 = sv.x; a1 = sv.y;
    } else {
        a0 = gB[(size_t)v * D];
    }

    const int s = offsets[v], e = offsets[v + 1];
    int j = s;
    for (; j + 2 <= e; j += 2) {
        int u0 = csr[j], u1 = csr[j + 1];
        if (VEC == 2) {
            float2 x0 = *reinterpret_cast<const float2*>(&gB[(size_t)u0 * D]);
            float2 x1 = *reinterpret_cast<const float2*>(&gB[(size_t)u1 * D]);
            a0 += x0.x; a1 += x0.y;
            c0 += x1.x; c1 += x1.y;
        } else {
            float x0 = gB[(size_t)u0 * D];
            float x1 = gB[(size_t)u1 * D];
            a0 += x0; c0 += x1;
        }
    }
    if (j < e) {
        int u = csr[j];
        if (VEC == 2) {
            float2 x = *reinterpret_cast<const float2*>(&gB[(size_t)u * D]);
            a0 += x.x; a1 += x.y;
        } else {
            a0 += gB[(size_t)u * D];
        }
    }
    a0 += c0; a1 += c1;

    const float dv = dinv[v];
    float o0 = dv * a0 + bias[col];
    if (RELU) o0 = fmaxf(o0, 0.f);
    if (VEC == 2) {
        float o1 = dv * a1 + bias[col + 1];
        if (RELU) o1 = fmaxf(o1, 0.f);
        *reinterpret_cast<float2*>(&out[(size_t)v * D + col]) = make_float2(o0, o1);
    } else {
        out[(size_t)v * D + col] = o0;
    }
}

// ---------------- launch ----------------

extern "C" void kernel_launch(void* const* d_in, const int* in_sizes, int n_in,
                              void* d_out, int out_size, void* d_ws, size_t ws_size,
                              hipStream_t stream) {
    const int N = 50000, E = 800000;
    const int NB = (N + 255) / 256;  // 196 scan blocks (<= 256)
    const float* x  = (const float*)d_in[0];
    const int* ei = (const int*)d_in[1];   // harness converts int64 -> int32
    const int* src = ei;
    const int* dst = ei + E;
    const float* W1 = (const float*)d_in[2]; const float* b1 = (const float*)d_in[3];
    const float* W2 = (const float*)d_in[4]; const float* b2 = (const float*)d_in[5];
    const float* W3 = (const float*)d_in[6]; const float* b3 = (const float*)d_in[7];
    float* out = (float*)d_out;

    char* ws = (char*)d_ws;
    size_t off = 0;
    auto alloc = [&](size_t bytes) -> void* {
        void* p = ws + off;
        off = (off + bytes + 255) & ~(size_t)255;
        return p;
    };
    int*   cnt     = (int*)alloc((size_t)N * 4);
    int*   offsets = (int*)alloc((size_t)(N + 1) * 4);
    int*   cursor  = (int*)alloc((size_t)N * 4);
    float* dinv    = (float*)alloc((size_t)N * 4);
    int*   csr     = (int*)alloc((size_t)E * 4);
    float* g       = (float*)alloc((size_t)N * 128 * 4);
    float* h       = (float*)alloc((size_t)N * 128 * 4);
    int*   bsum    = (int*)alloc((size_t)256 * 4);
    int*   bbase   = (int*)alloc((size_t)256 * 4);
    (void)ws_size; (void)n_in; (void)in_sizes; (void)out_size;

    // CSR build (dst-keyed; stores src)
    zero_kernel<<<(N + 255) / 256, 256, 0, stream>>>(cnt, N);
    count_kernel<<<(E + 255) / 256, 256, 0, stream>>>(dst, E, cnt, N);
    block_reduce_kernel<<<NB, 256, 0, stream>>>(cnt, N, bsum);
    scan_partials_kernel<<<1, 256, 0, stream>>>(bsum, NB, bbase, &offsets[N]);
    write_offsets_kernel<<<NB, 256, 0, stream>>>(cnt, N, bbase, offsets, cursor, dinv);
    fill_kernel<<<(E + 255) / 256, 256, 0, stream>>>(src, dst, E, cursor, csr, N);

    // layer 1: 128 -> 128, relu
    gemm_scale_kernel<128, 128, 32><<<(N + 31) / 32, 256, 0, stream>>>(x, W1, dinv, g, N);
    aggregate_kernel<128, true><<<(N + 3) / 4, 256, 0, stream>>>(g, offsets, csr, dinv, b1, h, N);
    // layer 2: 128 -> 64, relu
    gemm_scale_kernel<128, 64, 32><<<(N + 31) / 32, 256, 0, stream>>>(h, W2, dinv, g, N);
    aggregate_kernel<64, true><<<(N + 3) / 4, 256, 0, stream>>>(g, offsets, csr, dinv, b2, h, N);
    // layer 3: 64 -> 32, no relu -> d_out
    gemm_scale_kernel<64, 32, 32><<<(N + 31) / 32, 256, 0, stream>>>(h, W3, dinv, g, N);
    aggregate_kernel<32, false><<<(N + 7) / 8, 256, 0, stream>>>(g, offsets, csr, dinv, b3, out, N);
}

// Round 4
// 248.624 us; speedup vs baseline: 1.7916x; 1.2940x over previous
//
#include <hip/hip_runtime.h>
#include <hip/hip_bf16.h>
#include <cstdint>

// bf16 helpers (finite values only)
__device__ __forceinline__ unsigned f2bf_bits(float f) {
    unsigned u = __float_as_uint(f);
    return (u + 0x7fffu + ((u >> 16) & 1u)) >> 16;   // RNE
}
__device__ __forceinline__ float bf_lo(unsigned u) { return __uint_as_float(u << 16); }
__device__ __forceinline__ float bf_hi(unsigned u) { return __uint_as_float(u & 0xffff0000u); }

// ---------------- CSR build ----------------

__global__ __launch_bounds__(256) void zero_kernel(int* __restrict__ p, int n) {
    int i = blockIdx.x * 256 + threadIdx.x;
    if (i < n) p[i] = 0;
}

__global__ __launch_bounds__(256) void count_kernel(const int* __restrict__ dst, int E,
                                                    int* __restrict__ cnt, int n) {
    int e = blockIdx.x * 256 + threadIdx.x;
    if (e < E) {
        int d = dst[e];
        if (d >= 0 && d < n) atomicAdd(&cnt[d], 1);
    }
}

// two-level scan: (A) per-block sums, (B) scan partials, (C) write offsets
__global__ __launch_bounds__(256) void block_reduce_kernel(const int* __restrict__ cnt, int n,
                                                           int* __restrict__ bsum) {
    __shared__ int sh[256];
    const int t = threadIdx.x;
    const int i = blockIdx.x * 256 + t;
    sh[t] = (i < n) ? cnt[i] : 0;
    __syncthreads();
    for (int off = 128; off > 0; off >>= 1) {
        if (t < off) sh[t] += sh[t + off];
        __syncthreads();
    }
    if (t == 0) bsum[blockIdx.x] = sh[0];
}

__global__ __launch_bounds__(256) void scan_partials_kernel(const int* __restrict__ bsum, int nb,
                                                            int* __restrict__ bbase,
                                                            int* __restrict__ total_out) {
    __shared__ int sh[256];
    const int t = threadIdx.x;
    const int v = (t < nb) ? bsum[t] : 0;
    sh[t] = v;
    __syncthreads();
    for (int off = 1; off < 256; off <<= 1) {
        int val = (t >= off) ? sh[t - off] : 0;
        __syncthreads();
        sh[t] += val;
        __syncthreads();
    }
    bbase[t] = sh[t] - v;                    // exclusive base for block t
    if (t == nb - 1) total_out[0] = sh[t];   // offsets[n]
}

__global__ __launch_bounds__(256) void write_offsets_kernel(const int* __restrict__ cnt, int n,
                                                            const int* __restrict__ bbase,
                                                            int* __restrict__ offsets,
                                                            int* __restrict__ cursor,
                                                            float* __restrict__ dinv) {
    __shared__ int sh[256];
    const int t = threadIdx.x;
    const int i = blockIdx.x * 256 + t;
    const int c = (i < n) ? cnt[i] : 0;
    sh[t] = c;
    __syncthreads();
    for (int off = 1; off < 256; off <<= 1) {
        int val = (t >= off) ? sh[t - off] : 0;
        __syncthreads();
        sh[t] += val;
        __syncthreads();
    }
    if (i < n) {
        int excl = sh[t] - c + bbase[blockIdx.x];
        offsets[i] = excl;
        cursor[i] = excl;
        dinv[i] = rsqrtf((float)(c + 1));  // +1 self-loop; deg >= 1 always
    }
}

__global__ __launch_bounds__(256) void fill_kernel(const int* __restrict__ src,
                                                   const int* __restrict__ dst, int E,
                                                   int* __restrict__ cursor, int* __restrict__ csr,
                                                   int n) {
    int e = blockIdx.x * 256 + threadIdx.x;
    if (e < E) {
        int d = dst[e];
        int s = src[e];
        if (d >= 0 && d < n && s >= 0 && s < n) {
            int pos = atomicAdd(&cursor[d], 1);
            csr[pos] = s;
        }
    }
}

// ------- GEMM with dinv-scale epilogue, bf16 output: G = bf16( diag(dinv) * (X @ W) ) -------

template<int DIN, int DOUT, int ROWS>
__global__ __launch_bounds__(256) void gemm_scale_kernel(const float* __restrict__ X,
                                                         const float* __restrict__ W,
                                                         const float* __restrict__ dinv,
                                                         unsigned* __restrict__ G, int n) {
    constexpr int CG  = DOUT / 4;     // col groups (each thread does 4 cols)
    constexpr int RG  = 256 / CG;     // row groups
    constexpr int RPT = ROWS / RG;    // rows per thread
    constexpr int PAD = (DIN * DOUT * 4 > 32768) ? 0 : 4;
    constexpr int XS  = DIN + PAD;
    __shared__ float Ws[DIN * DOUT];
    __shared__ float Xs[ROWS * XS];
    const int t = threadIdx.x;
    const int row0 = blockIdx.x * ROWS;

    for (int i = t * 4; i < DIN * DOUT; i += 256 * 4)
        *reinterpret_cast<float4*>(&Ws[i]) = *reinterpret_cast<const float4*>(&W[i]);
    for (int i = t * 4; i < ROWS * DIN; i += 256 * 4) {
        int r = i / DIN, k = i % DIN;
        float4 v = make_float4(0.f, 0.f, 0.f, 0.f);
        if (row0 + r < n) v = *reinterpret_cast<const float4*>(&X[(size_t)(row0 + r) * DIN + k]);
        *reinterpret_cast<float4*>(&Xs[r * XS + k]) = v;
    }
    __syncthreads();

    const int tx = t % CG, ty = t / CG;
    float acc[RPT][4];
#pragma unroll
    for (int rr = 0; rr < RPT; ++rr) {
        acc[rr][0] = 0.f; acc[rr][1] = 0.f; acc[rr][2] = 0.f; acc[rr][3] = 0.f;
    }

#pragma unroll 4
    for (int k = 0; k < DIN; ++k) {
        float4 w = *reinterpret_cast<const float4*>(&Ws[k * DOUT + tx * 4]);
#pragma unroll
        for (int rr = 0; rr < RPT; ++rr) {
            float xv = Xs[(ty * RPT + rr) * XS + k];
            acc[rr][0] += xv * w.x;
            acc[rr][1] += xv * w.y;
            acc[rr][2] += xv * w.z;
            acc[rr][3] += xv * w.w;
        }
    }

#pragma unroll
    for (int rr = 0; rr < RPT; ++rr) {
        int r = row0 + ty * RPT + rr;
        if (r < n) {
            float s = dinv[r];
            unsigned p0 = f2bf_bits(acc[rr][0] * s) | (f2bf_bits(acc[rr][1] * s) << 16);
            unsigned p1 = f2bf_bits(acc[rr][2] * s) | (f2bf_bits(acc[rr][3] * s) << 16);
            *reinterpret_cast<uint2*>(&G[(size_t)r * (DOUT / 2) + tx * 2]) = make_uint2(p0, p1);
        }
    }
}

// -------- Aggregate: out[v] = act( dinv[v] * (g[v] + sum_{u in adj(v)} g[u]) + b ) --------
// G is bf16 (packed pairs in unsigned). Each lane handles 2 columns via one 4B load.

template<int D, bool RELU>
__global__ __launch_bounds__(256) void aggregate_kernel(const unsigned* __restrict__ G,
                                                        const int* __restrict__ offsets,
                                                        const int* __restrict__ csr,
                                                        const float* __restrict__ dinv,
                                                        const float* __restrict__ bias,
                                                        float* __restrict__ out, int n) {
    constexpr int W   = D / 2;        // uints per row
    constexpr int LPN = W;            // lanes per node (64 for D=128, 32 for 64, 16 for 32)
    constexpr int NPW = 64 / LPN;     // nodes per wave
    const int lane = threadIdx.x & 63;
    const int wave = (int)((blockIdx.x * 256 + threadIdx.x) >> 6);
    const int v = wave * NPW + lane / LPN;
    if (v >= n) return;
    const int cw  = lane % LPN;       // uint (column-pair) index within row
    const int col = cw * 2;

    // self term
    unsigned us = G[(size_t)v * W + cw];
    float a0 = bf_lo(us), a1 = bf_hi(us);
    float b0 = 0.f, b1 = 0.f, c0 = 0.f, c1 = 0.f, d0 = 0.f, d1 = 0.f;

    const int s = offsets[v], e = offsets[v + 1];
    int j = s;
    for (; j + 4 <= e; j += 4) {
        unsigned u0 = G[(size_t)csr[j]     * W + cw];
        unsigned u1 = G[(size_t)csr[j + 1] * W + cw];
        unsigned u2 = G[(size_t)csr[j + 2] * W + cw];
        unsigned u3 = G[(size_t)csr[j + 3] * W + cw];
        a0 += bf_lo(u0); a1 += bf_hi(u0);
        b0 += bf_lo(u1); b1 += bf_hi(u1);
        c0 += bf_lo(u2); c1 += bf_hi(u2);
        d0 += bf_lo(u3); d1 += bf_hi(u3);
    }
    for (; j < e; ++j) {
        unsigned u0 = G[(size_t)csr[j] * W + cw];
        a0 += bf_lo(u0); a1 += bf_hi(u0);
    }
    a0 += b0 + c0 + d0;
    a1 += b1 + c1 + d1;

    const float dv = dinv[v];
    float o0 = dv * a0 + bias[col];
    float o1 = dv * a1 + bias[col + 1];
    if (RELU) { o0 = fmaxf(o0, 0.f); o1 = fmaxf(o1, 0.f); }
    *reinterpret_cast<float2*>(&out[(size_t)v * D + col]) = make_float2(o0, o1);
}

// ---------------- launch ----------------

extern "C" void kernel_launch(void* const* d_in, const int* in_sizes, int n_in,
                              void* d_out, int out_size, void* d_ws, size_t ws_size,
                              hipStream_t stream) {
    const int N = 50000, E = 800000;
    const int NB = (N + 255) / 256;  // 196 scan blocks (<= 256)
    const float* x  = (const float*)d_in[0];
    const int* ei = (const int*)d_in[1];   // harness converts int64 -> int32
    const int* src = ei;
    const int* dst = ei + E;
    const float* W1 = (const float*)d_in[2]; const float* b1 = (const float*)d_in[3];
    const float* W2 = (const float*)d_in[4]; const float* b2 = (const float*)d_in[5];
    const float* W3 = (const float*)d_in[6]; const float* b3 = (const float*)d_in[7];
    float* out = (float*)d_out;

    char* ws = (char*)d_ws;
    size_t off = 0;
    auto alloc = [&](size_t bytes) -> void* {
        void* p = ws + off;
        off = (off + bytes + 255) & ~(size_t)255;
        return p;
    };
    int*      cnt     = (int*)alloc((size_t)N * 4);
    int*      offsets = (int*)alloc((size_t)(N + 1) * 4);
    int*      cursor  = (int*)alloc((size_t)N * 4);
    float*    dinv    = (float*)alloc((size_t)N * 4);
    int*      csr     = (int*)alloc((size_t)E * 4);
    unsigned* g       = (unsigned*)alloc((size_t)N * 64 * 4);  // bf16 pairs, up to D=128
    float*    h       = (float*)alloc((size_t)N * 128 * 4);
    int*      bsum    = (int*)alloc((size_t)256 * 4);
    int*      bbase   = (int*)alloc((size_t)256 * 4);
    (void)ws_size; (void)n_in; (void)in_sizes; (void)out_size;

    // CSR build (dst-keyed; stores src)
    zero_kernel<<<(N + 255) / 256, 256, 0, stream>>>(cnt, N);
    count_kernel<<<(E + 255) / 256, 256, 0, stream>>>(dst, E, cnt, N);
    block_reduce_kernel<<<NB, 256, 0, stream>>>(cnt, N, bsum);
    scan_partials_kernel<<<1, 256, 0, stream>>>(bsum, NB, bbase, &offsets[N]);
    write_offsets_kernel<<<NB, 256, 0, stream>>>(cnt, N, bbase, offsets, cursor, dinv);
    fill_kernel<<<(E + 255) / 256, 256, 0, stream>>>(src, dst, E, cursor, csr, N);

    // layer 1: 128 -> 128, relu
    gemm_scale_kernel<128, 128, 32><<<(N + 31) / 32, 256, 0, stream>>>(x, W1, dinv, g, N);
    aggregate_kernel<128, true><<<(N * 1 + 3) / 4, 256, 0, stream>>>(g, offsets, csr, dinv, b1, h, N);
    // layer 2: 128 -> 64, relu
    gemm_scale_kernel<128, 64, 32><<<(N + 31) / 32, 256, 0, stream>>>(h, W2, dinv, g, N);
    aggregate_kernel<64, true><<<(N + 7) / 8, 256, 0, stream>>>(g, offsets, csr, dinv, b2, h, N);
    // layer 3: 64 -> 32, no relu -> d_out
    gemm_scale_kernel<64, 32, 32><<<(N + 31) / 32, 256, 0, stream>>>(h, W3, dinv, g, N);
    aggregate_kernel<32, false><<<(N + 15) / 16, 256, 0, stream>>>(g, offsets, csr, dinv, b3, out, N);
}

// Round 5
// 231.699 us; speedup vs baseline: 1.9225x; 1.0730x over previous
//
#include <hip/hip_runtime.h>
#include <hip/hip_bf16.h>
#include <cstdint>

// bf16 helpers (finite values only)
__device__ __forceinline__ unsigned f2bf_bits(float f) {
    unsigned u = __float_as_uint(f);
    return (u + 0x7fffu + ((u >> 16) & 1u)) >> 16;   // RNE
}
__device__ __forceinline__ float bf_lo(unsigned u) { return __uint_as_float(u << 16); }
__device__ __forceinline__ float bf_hi(unsigned u) { return __uint_as_float(u & 0xffff0000u); }

// ---------------- CSR build ----------------

__global__ __launch_bounds__(256) void zero_kernel(int* __restrict__ p, int n) {
    int i = blockIdx.x * 256 + threadIdx.x;
    if (i < n) p[i] = 0;
}

__global__ __launch_bounds__(256) void count_kernel(const int* __restrict__ dst, int E,
                                                    int* __restrict__ cnt, int n) {
    int e = blockIdx.x * 256 + threadIdx.x;
    if (e < E) {
        int d = dst[e];
        if (d >= 0 && d < n) atomicAdd(&cnt[d], 1);
    }
}

// two-level scan: (A) per-block sums, (B) scan partials, (C) write offsets
__global__ __launch_bounds__(256) void block_reduce_kernel(const int* __restrict__ cnt, int n,
                                                           int* __restrict__ bsum) {
    __shared__ int sh[256];
    const int t = threadIdx.x;
    const int i = blockIdx.x * 256 + t;
    sh[t] = (i < n) ? cnt[i] : 0;
    __syncthreads();
    for (int off = 128; off > 0; off >>= 1) {
        if (t < off) sh[t] += sh[t + off];
        __syncthreads();
    }
    if (t == 0) bsum[blockIdx.x] = sh[0];
}

__global__ __launch_bounds__(256) void scan_partials_kernel(const int* __restrict__ bsum, int nb,
                                                            int* __restrict__ bbase,
                                                            int* __restrict__ total_out) {
    __shared__ int sh[256];
    const int t = threadIdx.x;
    const int v = (t < nb) ? bsum[t] : 0;
    sh[t] = v;
    __syncthreads();
    for (int off = 1; off < 256; off <<= 1) {
        int val = (t >= off) ? sh[t - off] : 0;
        __syncthreads();
        sh[t] += val;
        __syncthreads();
    }
    bbase[t] = sh[t] - v;                    // exclusive base for block t
    if (t == nb - 1) total_out[0] = sh[t];   // offsets[n]
}

// writes offsets/dinv and seeds per-bucket cursors (bucket = 256 nodes)
__global__ __launch_bounds__(256) void write_offsets_kernel(const int* __restrict__ cnt, int n,
                                                            const int* __restrict__ bbase,
                                                            int* __restrict__ offsets,
                                                            int* __restrict__ bkt_cursor,
                                                            float* __restrict__ dinv) {
    __shared__ int sh[256];
    const int t = threadIdx.x;
    const int i = blockIdx.x * 256 + t;
    const int c = (i < n) ? cnt[i] : 0;
    sh[t] = c;
    __syncthreads();
    for (int off = 1; off < 256; off <<= 1) {
        int val = (t >= off) ? sh[t - off] : 0;
        __syncthreads();
        sh[t] += val;
        __syncthreads();
    }
    if (i < n) {
        int excl = sh[t] - c + bbase[blockIdx.x];
        offsets[i] = excl;
        if (t == 0) bkt_cursor[blockIdx.x] = excl;  // bucket b = block b (256 nodes)
        dinv[i] = rsqrtf((float)(c + 1));  // +1 self-loop; deg >= 1 always
    }
}

// Phase A: bin edges into 256-node buckets, bucket layout == csr layout.
// 4096 edges per block, LDS-staged so global writes are segment-coalesced.
__global__ __launch_bounds__(256) void bin_kernel(const int* __restrict__ src,
                                                  const int* __restrict__ dst, int E,
                                                  int* __restrict__ bkt_cursor,
                                                  uint2* __restrict__ bin, int n) {
    __shared__ int qcnt[256];
    __shared__ int qofs[256];
    __shared__ int gbase[256];
    __shared__ uint2 staging[4096];
    const int t = threadIdx.x;
    const int e0 = blockIdx.x * 4096;
    qcnt[t] = 0;
    __syncthreads();

    int sa[16], da[16], slot[16];
#pragma unroll
    for (int k = 0; k < 16; ++k) {
        int e = e0 + k * 256 + t;
        sa[k] = -1; da[k] = 0; slot[k] = 0;
        if (e < E) {
            int ss = src[e], dd = dst[e];
            if (ss >= 0 && ss < n && dd >= 0 && dd < n) {
                sa[k] = ss; da[k] = dd;
                slot[k] = atomicAdd(&qcnt[dd >> 8], 1);
            }
        }
    }
    __syncthreads();

    // inclusive scan of qcnt into qofs
    qofs[t] = qcnt[t];
    __syncthreads();
    for (int off = 1; off < 256; off <<= 1) {
        int val = (t >= off) ? qofs[t - off] : 0;
        __syncthreads();
        qofs[t] += val;
        __syncthreads();
    }
    const int tot = qofs[255];
    const int myc = qcnt[t];
    if (myc > 0) gbase[t] = atomicAdd(&bkt_cursor[t], myc);
    __syncthreads();
    qofs[t] -= qcnt[t];           // exclusive
    __syncthreads();

#pragma unroll
    for (int k = 0; k < 16; ++k) {
        if (sa[k] >= 0)
            staging[qofs[da[k] >> 8] + slot[k]] = make_uint2((unsigned)sa[k], (unsigned)da[k]);
    }
    __syncthreads();

    for (int i = t; i < tot; i += 256) {
        uint2 en = staging[i];
        int b = (int)(en.y >> 8);
        bin[(size_t)gbase[b] + (i - qofs[b])] = en;
    }
}

// Phase B: per-bucket fill; LDS node cursors; csr writes land in the block's contiguous slice.
__global__ __launch_bounds__(256) void fill2_kernel(const int* __restrict__ offsets,
                                                    const uint2* __restrict__ bin,
                                                    int* __restrict__ csr, int n) {
    __shared__ int cur[256];
    const int t = threadIdx.x;
    const int node0 = blockIdx.x * 256;
    if (node0 + t < n) cur[t] = offsets[node0 + t];
    __syncthreads();
    const int S  = offsets[node0];
    const int Eo = offsets[min(node0 + 256, n)];
    for (int i = S + t; i < Eo; i += 256) {
        uint2 en = bin[i];
        int pos = atomicAdd(&cur[(int)en.y - node0], 1);
        csr[pos] = (int)en.x;
    }
}

// ------- GEMM with dinv-scale epilogue, bf16 output: G = bf16( diag(dinv) * (X @ W) ) -------

template<int DIN, int DOUT, int ROWS>
__global__ __launch_bounds__(256) void gemm_scale_kernel(const float* __restrict__ X,
                                                         const float* __restrict__ W,
                                                         const float* __restrict__ dinv,
                                                         unsigned* __restrict__ G, int n) {
    constexpr int CG  = DOUT / 4;     // col groups (each thread does 4 cols)
    constexpr int RG  = 256 / CG;     // row groups
    constexpr int RPT = ROWS / RG;    // rows per thread
    constexpr int PAD = (DIN * DOUT * 4 > 32768) ? 0 : 4;
    constexpr int XS  = DIN + PAD;
    __shared__ float Ws[DIN * DOUT];
    __shared__ float Xs[ROWS * XS];
    const int t = threadIdx.x;
    const int row0 = blockIdx.x * ROWS;

    for (int i = t * 4; i < DIN * DOUT; i += 256 * 4)
        *reinterpret_cast<float4*>(&Ws[i]) = *reinterpret_cast<const float4*>(&W[i]);
    for (int i = t * 4; i < ROWS * DIN; i += 256 * 4) {
        int r = i / DIN, k = i % DIN;
        float4 v = make_float4(0.f, 0.f, 0.f, 0.f);
        if (row0 + r < n) v = *reinterpret_cast<const float4*>(&X[(size_t)(row0 + r) * DIN + k]);
        *reinterpret_cast<float4*>(&Xs[r * XS + k]) = v;
    }
    __syncthreads();

    const int tx = t % CG, ty = t / CG;
    float acc[RPT][4];
#pragma unroll
    for (int rr = 0; rr < RPT; ++rr) {
        acc[rr][0] = 0.f; acc[rr][1] = 0.f; acc[rr][2] = 0.f; acc[rr][3] = 0.f;
    }

#pragma unroll 4
    for (int k = 0; k < DIN; ++k) {
        float4 w = *reinterpret_cast<const float4*>(&Ws[k * DOUT + tx * 4]);
#pragma unroll
        for (int rr = 0; rr < RPT; ++rr) {
            float xv = Xs[(ty * RPT + rr) * XS + k];
            acc[rr][0] += xv * w.x;
            acc[rr][1] += xv * w.y;
            acc[rr][2] += xv * w.z;
            acc[rr][3] += xv * w.w;
        }
    }

#pragma unroll
    for (int rr = 0; rr < RPT; ++rr) {
        int r = row0 + ty * RPT + rr;
        if (r < n) {
            float s = dinv[r];
            unsigned p0 = f2bf_bits(acc[rr][0] * s) | (f2bf_bits(acc[rr][1] * s) << 16);
            unsigned p1 = f2bf_bits(acc[rr][2] * s) | (f2bf_bits(acc[rr][3] * s) << 16);
            *reinterpret_cast<uint2*>(&G[(size_t)r * (DOUT / 2) + tx * 2]) = make_uint2(p0, p1);
        }
    }
}

// -------- Aggregate: out[v] = act( dinv[v] * (g[v] + sum_{u in adj(v)} g[u]) + b ) --------
// G is bf16 (packed pairs in unsigned). Each lane handles 2 columns via one 4B load.

template<int D, bool RELU>
__global__ __launch_bounds__(256) void aggregate_kernel(const unsigned* __restrict__ G,
                                                        const int* __restrict__ offsets,
                                                        const int* __restrict__ csr,
                                                        const float* __restrict__ dinv,
                                                        const float* __restrict__ bias,
                                                        float* __restrict__ out, int n) {
    constexpr int W   = D / 2;        // uints per row
    constexpr int LPN = W;            // lanes per node (64 for D=128, 32 for 64, 16 for 32)
    constexpr int NPW = 64 / LPN;     // nodes per wave
    const int lane = threadIdx.x & 63;
    const int wave = (int)((blockIdx.x * 256 + threadIdx.x) >> 6);
    const int v = wave * NPW + lane / LPN;
    if (v >= n) return;
    const int cw  = lane % LPN;       // uint (column-pair) index within row
    const int col = cw * 2;

    // self term
    unsigned us = G[(size_t)v * W + cw];
    float a0 = bf_lo(us), a1 = bf_hi(us);
    float b0 = 0.f, b1 = 0.f, c0 = 0.f, c1 = 0.f, d0 = 0.f, d1 = 0.f;

    const int s = offsets[v], e = offsets[v + 1];
    int j = s;
    for (; j + 4 <= e; j += 4) {
        unsigned u0 = G[(size_t)csr[j]     * W + cw];
        unsigned u1 = G[(size_t)csr[j + 1] * W + cw];
        unsigned u2 = G[(size_t)csr[j + 2] * W + cw];
        unsigned u3 = G[(size_t)csr[j + 3] * W + cw];
        a0 += bf_lo(u0); a1 += bf_hi(u0);
        b0 += bf_lo(u1); b1 += bf_hi(u1);
        c0 += bf_lo(u2); c1 += bf_hi(u2);
        d0 += bf_lo(u3); d1 += bf_hi(u3);
    }
    for (; j < e; ++j) {
        unsigned u0 = G[(size_t)csr[j] * W + cw];
        a0 += bf_lo(u0); a1 += bf_hi(u0);
    }
    a0 += b0 + c0 + d0;
    a1 += b1 + c1 + d1;

    const float dv = dinv[v];
    float o0 = dv * a0 + bias[col];
    float o1 = dv * a1 + bias[col + 1];
    if (RELU) { o0 = fmaxf(o0, 0.f); o1 = fmaxf(o1, 0.f); }
    *reinterpret_cast<float2*>(&out[(size_t)v * D + col]) = make_float2(o0, o1);
}

// ---------------- launch ----------------

extern "C" void kernel_launch(void* const* d_in, const int* in_sizes, int n_in,
                              void* d_out, int out_size, void* d_ws, size_t ws_size,
                              hipStream_t stream) {
    const int N = 50000, E = 800000;
    const int NB = (N + 255) / 256;      // 196 node blocks == buckets
    const int NBE = (E + 4095) / 4096;   // 196 bin blocks
    const float* x  = (const float*)d_in[0];
    const int* ei = (const int*)d_in[1];   // harness converts int64 -> int32
    const int* src = ei;
    const int* dst = ei + E;
    const float* W1 = (const float*)d_in[2]; const float* b1 = (const float*)d_in[3];
    const float* W2 = (const float*)d_in[4]; const float* b2 = (const float*)d_in[5];
    const float* W3 = (const float*)d_in[6]; const float* b3 = (const float*)d_in[7];
    float* out = (float*)d_out;

    char* ws = (char*)d_ws;
    size_t off = 0;
    auto alloc = [&](size_t bytes) -> void* {
        void* p = ws + off;
        off = (off + bytes + 255) & ~(size_t)255;
        return p;
    };
    int*      cnt        = (int*)alloc((size_t)N * 4);
    int*      offsets    = (int*)alloc((size_t)(N + 1) * 4);
    float*    dinv       = (float*)alloc((size_t)N * 4);
    int*      csr        = (int*)alloc((size_t)E * 4);
    unsigned* g          = (unsigned*)alloc((size_t)N * 64 * 4);  // bf16 pairs, up to D=128
    float*    h          = (float*)alloc((size_t)N * 128 * 4);
    int*      bsum       = (int*)alloc((size_t)256 * 4);
    int*      bbase      = (int*)alloc((size_t)256 * 4);
    int*      bkt_cursor = (int*)alloc((size_t)256 * 4);
    uint2*    bin        = (uint2*)h;   // alias: bin consumed by fill2 before h is written
    (void)ws_size; (void)n_in; (void)in_sizes; (void)out_size;

    // CSR build (dst-keyed; stores src)
    zero_kernel<<<(N + 255) / 256, 256, 0, stream>>>(cnt, N);
    count_kernel<<<(E + 255) / 256, 256, 0, stream>>>(dst, E, cnt, N);
    block_reduce_kernel<<<NB, 256, 0, stream>>>(cnt, N, bsum);
    scan_partials_kernel<<<1, 256, 0, stream>>>(bsum, NB, bbase, &offsets[N]);
    write_offsets_kernel<<<NB, 256, 0, stream>>>(cnt, N, bbase, offsets, bkt_cursor, dinv);
    bin_kernel<<<NBE, 256, 0, stream>>>(src, dst, E, bkt_cursor, bin, N);
    fill2_kernel<<<NB, 256, 0, stream>>>(offsets, bin, csr, N);

    // layer 1: 128 -> 128, relu
    gemm_scale_kernel<128, 128, 32><<<(N + 31) / 32, 256, 0, stream>>>(x, W1, dinv, g, N);
    aggregate_kernel<128, true><<<(N + 3) / 4, 256, 0, stream>>>(g, offsets, csr, dinv, b1, h, N);
    // layer 2: 128 -> 64, relu
    gemm_scale_kernel<128, 64, 32><<<(N + 31) / 32, 256, 0, stream>>>(h, W2, dinv, g, N);
    aggregate_kernel<64, true><<<(N + 7) / 8, 256, 0, stream>>>(g, offsets, csr, dinv, b2, h, N);
    // layer 3: 64 -> 32, no relu -> d_out
    gemm_scale_kernel<64, 32, 32><<<(N + 31) / 32, 256, 0, stream>>>(h, W3, dinv, g, N);
    aggregate_kernel<32, false><<<(N + 15) / 16, 256, 0, stream>>>(g, offsets, csr, dinv, b3, out, N);
}

// Round 6
// 200.004 us; speedup vs baseline: 2.2272x; 1.1585x over previous
//
#include <hip/hip_runtime.h>
#include <hip/hip_bf16.h>
#include <cstdint>

using short8 = __attribute__((ext_vector_type(8))) short;
using f32x4  = __attribute__((ext_vector_type(4))) float;

// bf16 helpers (finite values only)
__device__ __forceinline__ unsigned f2bf_bits(float f) {
    unsigned u = __float_as_uint(f);
    return (u + 0x7fffu + ((u >> 16) & 1u)) >> 16;   // RNE
}
__device__ __forceinline__ float bf_lo(unsigned u) { return __uint_as_float(u << 16); }
__device__ __forceinline__ float bf_hi(unsigned u) { return __uint_as_float(u & 0xffff0000u); }

// ---------------- CSR build ----------------

__global__ __launch_bounds__(256) void zero_kernel(int* __restrict__ p, int n) {
    int i = blockIdx.x * 256 + threadIdx.x;
    if (i < n) p[i] = 0;
}

__global__ __launch_bounds__(256) void count_kernel(const int* __restrict__ dst, int E,
                                                    int* __restrict__ cnt, int n) {
    int e = blockIdx.x * 256 + threadIdx.x;
    if (e < E) {
        int d = dst[e];
        if (d >= 0 && d < n) atomicAdd(&cnt[d], 1);
    }
}

__global__ __launch_bounds__(256) void block_reduce_kernel(const int* __restrict__ cnt, int n,
                                                           int* __restrict__ bsum) {
    __shared__ int sh[256];
    const int t = threadIdx.x;
    const int i = blockIdx.x * 256 + t;
    sh[t] = (i < n) ? cnt[i] : 0;
    __syncthreads();
    for (int off = 128; off > 0; off >>= 1) {
        if (t < off) sh[t] += sh[t + off];
        __syncthreads();
    }
    if (t == 0) bsum[blockIdx.x] = sh[0];
}

__global__ __launch_bounds__(256) void scan_partials_kernel(const int* __restrict__ bsum, int nb,
                                                            int* __restrict__ bbase,
                                                            int* __restrict__ total_out) {
    __shared__ int sh[256];
    const int t = threadIdx.x;
    const int v = (t < nb) ? bsum[t] : 0;
    sh[t] = v;
    __syncthreads();
    for (int off = 1; off < 256; off <<= 1) {
        int val = (t >= off) ? sh[t - off] : 0;
        __syncthreads();
        sh[t] += val;
        __syncthreads();
    }
    bbase[t] = sh[t] - v;
    if (t == nb - 1) total_out[0] = sh[t];
}

__global__ __launch_bounds__(256) void write_offsets_kernel(const int* __restrict__ cnt, int n,
                                                            const int* __restrict__ bbase,
                                                            int* __restrict__ offsets,
                                                            int* __restrict__ bkt_cursor,
                                                            float* __restrict__ dinv) {
    __shared__ int sh[256];
    const int t = threadIdx.x;
    const int i = blockIdx.x * 256 + t;
    const int c = (i < n) ? cnt[i] : 0;
    sh[t] = c;
    __syncthreads();
    for (int off = 1; off < 256; off <<= 1) {
        int val = (t >= off) ? sh[t - off] : 0;
        __syncthreads();
        sh[t] += val;
        __syncthreads();
    }
    if (i < n) {
        int excl = sh[t] - c + bbase[blockIdx.x];
        offsets[i] = excl;
        if (t == 0) bkt_cursor[blockIdx.x] = excl;
        dinv[i] = rsqrtf((float)(c + 1));
    }
}

// Phase A: bin edges into 256-node buckets (bucket layout == csr layout), LDS-staged.
__global__ __launch_bounds__(256) void bin_kernel(const int* __restrict__ src,
                                                  const int* __restrict__ dst, int E,
                                                  int* __restrict__ bkt_cursor,
                                                  uint2* __restrict__ bin, int n) {
    __shared__ int qcnt[256];
    __shared__ int qofs[256];
    __shared__ int gbase[256];
    __shared__ uint2 staging[4096];
    const int t = threadIdx.x;
    const int e0 = blockIdx.x * 4096;
    qcnt[t] = 0;
    __syncthreads();

    int sa[16], da[16], slot[16];
#pragma unroll
    for (int k = 0; k < 16; ++k) {
        int e = e0 + k * 256 + t;
        sa[k] = -1; da[k] = 0; slot[k] = 0;
        if (e < E) {
            int ss = src[e], dd = dst[e];
            if (ss >= 0 && ss < n && dd >= 0 && dd < n) {
                sa[k] = ss; da[k] = dd;
                slot[k] = atomicAdd(&qcnt[dd >> 8], 1);
            }
        }
    }
    __syncthreads();

    qofs[t] = qcnt[t];
    __syncthreads();
    for (int off = 1; off < 256; off <<= 1) {
        int val = (t >= off) ? qofs[t - off] : 0;
        __syncthreads();
        qofs[t] += val;
        __syncthreads();
    }
    const int tot = qofs[255];
    const int myc = qcnt[t];
    if (myc > 0) gbase[t] = atomicAdd(&bkt_cursor[t], myc);
    __syncthreads();
    qofs[t] -= qcnt[t];
    __syncthreads();

#pragma unroll
    for (int k = 0; k < 16; ++k) {
        if (sa[k] >= 0)
            staging[qofs[da[k] >> 8] + slot[k]] = make_uint2((unsigned)sa[k], (unsigned)da[k]);
    }
    __syncthreads();

    for (int i = t; i < tot; i += 256) {
        uint2 en = staging[i];
        int b = (int)(en.y >> 8);
        bin[(size_t)gbase[b] + (i - qofs[b])] = en;
    }
}

// Phase B: per-bucket fill; LDS node cursors; csr writes contiguous per block.
__global__ __launch_bounds__(256) void fill2_kernel(const int* __restrict__ offsets,
                                                    const uint2* __restrict__ bin,
                                                    int* __restrict__ csr, int n) {
    __shared__ int cur[256];
    const int t = threadIdx.x;
    const int node0 = blockIdx.x * 256;
    if (node0 + t < n) cur[t] = offsets[node0 + t];
    __syncthreads();
    const int S  = offsets[node0];
    const int Eo = offsets[min(node0 + 256, n)];
    for (int i = S + t; i < Eo; i += 256) {
        uint2 en = bin[i];
        int pos = atomicAdd(&cur[(int)en.y - node0], 1);
        csr[pos] = (int)en.x;
    }
}

// ------- W pre-pack into MFMA A-fragment order, split hi/lo bf16 -------
// Frag (kk,ct), lane L: A[m = ct*16 + (L&15)][k = kk*32 + (L>>4)*8 + j], A = W^T (m = W col).

template<int DIN, int DOUT>
__global__ __launch_bounds__(256) void prepack_kernel(const float* __restrict__ W,
                                                      short* __restrict__ Wp_hi,
                                                      short* __restrict__ Wp_lo) {
    constexpr int NT = DOUT / 16;
    constexpr int NK = DIN / 32;
    const int total = NK * NT * 64;
    for (int idx = blockIdx.x * 256 + threadIdx.x; idx < total; idx += gridDim.x * 256) {
        int lane = idx & 63, tile = idx >> 6;
        int kk = tile / NT, ct = tile - kk * NT;
        int g = lane >> 4, cl = lane & 15;
        int c = ct * 16 + cl;
        short8 h8, l8;
#pragma unroll
        for (int j = 0; j < 8; ++j) {
            float w = W[(size_t)(kk * 32 + g * 8 + j) * DOUT + c];
            unsigned hb = f2bf_bits(w);
            unsigned lb = f2bf_bits(w - bf_lo(hb));
            h8[j] = (short)hb; l8[j] = (short)lb;
        }
        *reinterpret_cast<short8*>(&Wp_hi[(size_t)idx * 8]) = h8;
        *reinterpret_cast<short8*>(&Wp_lo[(size_t)idx * 8]) = l8;
    }
}

// ------- MFMA GEMM (split-bf16, fp32-grade): G = bf16( diag(dinv) * (X @ W) ) -------
// Computes out^T per tile: A = W^T frags (prepacked), B = X-row frags from LDS.
// 256 thr = 4 waves; block = 64 rows of X; each wave one 16-row strip × DOUT cols.

template<int DIN, int DOUT>
__global__ __launch_bounds__(256) void mfma_gemm_kernel(const float* __restrict__ X,
                                                        const short8* __restrict__ Wp_hi,
                                                        const short8* __restrict__ Wp_lo,
                                                        const float* __restrict__ dinv,
                                                        unsigned* __restrict__ G, int n) {
    constexpr int NT  = DOUT / 16;
    constexpr int NK  = DIN / 32;
    constexpr int WPR = DIN / 2;            // uint words per LDS row
    __shared__ unsigned Xh[64 * WPR];
    __shared__ unsigned Xl[64 * WPR];
    const int t = threadIdx.x;
    const int row0 = blockIdx.x * 64;

    // stage X tile, split into bf16 hi/lo, XOR-swizzled ((r&7)<<2 on word idx)
    for (int i = t * 4; i < 64 * DIN; i += 1024) {
        int r = i / DIN, c = i % DIN;
        float4 v = make_float4(0.f, 0.f, 0.f, 0.f);
        if (row0 + r < n) v = *reinterpret_cast<const float4*>(&X[(size_t)(row0 + r) * DIN + c]);
        unsigned h0 = f2bf_bits(v.x), h1 = f2bf_bits(v.y), h2 = f2bf_bits(v.z), h3 = f2bf_bits(v.w);
        unsigned l0 = f2bf_bits(v.x - bf_lo(h0)), l1 = f2bf_bits(v.y - bf_lo(h1));
        unsigned l2 = f2bf_bits(v.z - bf_lo(h2)), l3 = f2bf_bits(v.w - bf_lo(h3));
        int w = (r * WPR + c / 2) ^ ((r & 7) << 2);
        *reinterpret_cast<uint2*>(&Xh[w]) = make_uint2(h0 | (h1 << 16), h2 | (h3 << 16));
        *reinterpret_cast<uint2*>(&Xl[w]) = make_uint2(l0 | (l1 << 16), l2 | (l3 << 16));
    }
    __syncthreads();

    const int lane = t & 63, wid = t >> 6;
    const int g = lane >> 4, cl = lane & 15;
    const int lrow = wid * 16 + cl;          // X row (within block) this lane feeds as B-col
    f32x4 acc[NT];
#pragma unroll
    for (int i = 0; i < NT; ++i) acc[i] = (f32x4){0.f, 0.f, 0.f, 0.f};

#pragma unroll
    for (int kk = 0; kk < NK; ++kk) {
        int wb = (lrow * WPR + kk * 16 + g * 4) ^ ((lrow & 7) << 2);
        short8 xh = *reinterpret_cast<const short8*>(&Xh[wb]);
        short8 xl = *reinterpret_cast<const short8*>(&Xl[wb]);
#pragma unroll
        for (int ct = 0; ct < NT; ++ct) {
            short8 wh = Wp_hi[(kk * NT + ct) * 64 + lane];
            short8 wl = Wp_lo[(kk * NT + ct) * 64 + lane];
            acc[ct] = __builtin_amdgcn_mfma_f32_16x16x32_bf16(wh, xh, acc[ct], 0, 0, 0);
            acc[ct] = __builtin_amdgcn_mfma_f32_16x16x32_bf16(wh, xl, acc[ct], 0, 0, 0);
            acc[ct] = __builtin_amdgcn_mfma_f32_16x16x32_bf16(wl, xh, acc[ct], 0, 0, 0);
        }
    }

    // D^T: lane holds out[row = row0+lrow][cols ct*16 + g*4 + 0..3] -> pack bf16 pairs
    const int r = row0 + lrow;
    if (r < n) {
        const float s = dinv[r];
#pragma unroll
        for (int ct = 0; ct < NT; ++ct) {
            int c0 = ct * 16 + g * 4;
            unsigned p0 = f2bf_bits(acc[ct][0] * s) | (f2bf_bits(acc[ct][1] * s) << 16);
            unsigned p1 = f2bf_bits(acc[ct][2] * s) | (f2bf_bits(acc[ct][3] * s) << 16);
            *reinterpret_cast<uint2*>(&G[(size_t)r * (DOUT / 2) + c0 / 2]) = make_uint2(p0, p1);
        }
    }
}

// -------- Aggregate: out[v] = act( dinv[v] * (g[v] + sum_u g[u]) + b ), g bf16-packed --------

template<int D, bool RELU>
__global__ __launch_bounds__(256) void aggregate_kernel(const unsigned* __restrict__ G,
                                                        const int* __restrict__ offsets,
                                                        const int* __restrict__ csr,
                                                        const float* __restrict__ dinv,
                                                        const float* __restrict__ bias,
                                                        float* __restrict__ out, int n) {
    constexpr int W   = D / 2;
    constexpr int LPN = W;
    constexpr int NPW = 64 / LPN;
    const int lane = threadIdx.x & 63;
    const int wave = (int)((blockIdx.x * 256 + threadIdx.x) >> 6);
    const int v = wave * NPW + lane / LPN;
    if (v >= n) return;
    const int cw  = lane % LPN;
    const int col = cw * 2;

    unsigned us = G[(size_t)v * W + cw];
    float a0 = bf_lo(us), a1 = bf_hi(us);
    float b0 = 0.f, b1 = 0.f, c0 = 0.f, c1 = 0.f, d0 = 0.f, d1 = 0.f;

    const int s = offsets[v], e = offsets[v + 1];
    int j = s;
    for (; j + 4 <= e; j += 4) {
        unsigned u0 = G[(size_t)csr[j]     * W + cw];
        unsigned u1 = G[(size_t)csr[j + 1] * W + cw];
        unsigned u2 = G[(size_t)csr[j + 2] * W + cw];
        unsigned u3 = G[(size_t)csr[j + 3] * W + cw];
        a0 += bf_lo(u0); a1 += bf_hi(u0);
        b0 += bf_lo(u1); b1 += bf_hi(u1);
        c0 += bf_lo(u2); c1 += bf_hi(u2);
        d0 += bf_lo(u3); d1 += bf_hi(u3);
    }
    for (; j < e; ++j) {
        unsigned u0 = G[(size_t)csr[j] * W + cw];
        a0 += bf_lo(u0); a1 += bf_hi(u0);
    }
    a0 += b0 + c0 + d0;
    a1 += b1 + c1 + d1;

    const float dv = dinv[v];
    float o0 = dv * a0 + bias[col];
    float o1 = dv * a1 + bias[col + 1];
    if (RELU) { o0 = fmaxf(o0, 0.f); o1 = fmaxf(o1, 0.f); }
    *reinterpret_cast<float2*>(&out[(size_t)v * D + col]) = make_float2(o0, o1);
}

// ---------------- launch ----------------

extern "C" void kernel_launch(void* const* d_in, const int* in_sizes, int n_in,
                              void* d_out, int out_size, void* d_ws, size_t ws_size,
                              hipStream_t stream) {
    const int N = 50000, E = 800000;
    const int NB = (N + 255) / 256;
    const int NBE = (E + 4095) / 4096;
    const int NG = (N + 63) / 64;
    const float* x  = (const float*)d_in[0];
    const int* ei = (const int*)d_in[1];
    const int* src = ei;
    const int* dst = ei + E;
    const float* W1 = (const float*)d_in[2]; const float* b1 = (const float*)d_in[3];
    const float* W2 = (const float*)d_in[4]; const float* b2 = (const float*)d_in[5];
    const float* W3 = (const float*)d_in[6]; const float* b3 = (const float*)d_in[7];
    float* out = (float*)d_out;

    char* ws = (char*)d_ws;
    size_t off = 0;
    auto alloc = [&](size_t bytes) -> void* {
        void* p = ws + off;
        off = (off + bytes + 255) & ~(size_t)255;
        return p;
    };
    int*      cnt        = (int*)alloc((size_t)N * 4);
    int*      offsets    = (int*)alloc((size_t)(N + 1) * 4);
    float*    dinv       = (float*)alloc((size_t)N * 4);
    int*      csr        = (int*)alloc((size_t)E * 4);
    unsigned* g          = (unsigned*)alloc((size_t)N * 64 * 4);
    float*    h          = (float*)alloc((size_t)N * 128 * 4);
    int*      bsum       = (int*)alloc((size_t)256 * 4);
    int*      bbase      = (int*)alloc((size_t)256 * 4);
    int*      bkt_cursor = (int*)alloc((size_t)256 * 4);
    short*    wp1h = (short*)alloc((size_t)128 * 128 * 2);
    short*    wp1l = (short*)alloc((size_t)128 * 128 * 2);
    short*    wp2h = (short*)alloc((size_t)128 * 64 * 2);
    short*    wp2l = (short*)alloc((size_t)128 * 64 * 2);
    short*    wp3h = (short*)alloc((size_t)64 * 32 * 2);
    short*    wp3l = (short*)alloc((size_t)64 * 32 * 2);
    uint2*    bin        = (uint2*)h;   // alias: bin consumed by fill2 before h is written
    (void)ws_size; (void)n_in; (void)in_sizes; (void)out_size;

    // W pre-pack (independent of CSR chain)
    prepack_kernel<128, 128><<<8, 256, 0, stream>>>(W1, wp1h, wp1l);
    prepack_kernel<128, 64><<<4, 256, 0, stream>>>(W2, wp2h, wp2l);
    prepack_kernel<64, 32><<<1, 256, 0, stream>>>(W3, wp3h, wp3l);

    // CSR build (dst-keyed; stores src)
    zero_kernel<<<(N + 255) / 256, 256, 0, stream>>>(cnt, N);
    count_kernel<<<(E + 255) / 256, 256, 0, stream>>>(dst, E, cnt, N);
    block_reduce_kernel<<<NB, 256, 0, stream>>>(cnt, N, bsum);
    scan_partials_kernel<<<1, 256, 0, stream>>>(bsum, NB, bbase, &offsets[N]);
    write_offsets_kernel<<<NB, 256, 0, stream>>>(cnt, N, bbase, offsets, bkt_cursor, dinv);
    bin_kernel<<<NBE, 256, 0, stream>>>(src, dst, E, bkt_cursor, bin, N);
    fill2_kernel<<<NB, 256, 0, stream>>>(offsets, bin, csr, N);

    // layer 1: 128 -> 128, relu
    mfma_gemm_kernel<128, 128><<<NG, 256, 0, stream>>>(x, (const short8*)wp1h, (const short8*)wp1l, dinv, g, N);
    aggregate_kernel<128, true><<<(N + 3) / 4, 256, 0, stream>>>(g, offsets, csr, dinv, b1, h, N);
    // layer 2: 128 -> 64, relu
    mfma_gemm_kernel<128, 64><<<NG, 256, 0, stream>>>(h, (const short8*)wp2h, (const short8*)wp2l, dinv, g, N);
    aggregate_kernel<64, true><<<(N + 7) / 8, 256, 0, stream>>>(g, offsets, csr, dinv, b2, h, N);
    // layer 3: 64 -> 32, no relu -> d_out
    mfma_gemm_kernel<64, 32><<<NG, 256, 0, stream>>>(h, (const short8*)wp3h, (const short8*)wp3l, dinv, g, N);
    aggregate_kernel<32, false><<<(N + 15) / 16, 256, 0, stream>>>(g, offsets, csr, dinv, b3, out, N);
}

// Round 7
// 158.178 us; speedup vs baseline: 2.8161x; 1.2644x over previous
//
#include <hip/hip_runtime.h>
#include <hip/hip_bf16.h>
#include <cstdint>

using short8 = __attribute__((ext_vector_type(8))) short;
using f32x4  = __attribute__((ext_vector_type(4))) float;

// bf16 helpers (finite values only)
__device__ __forceinline__ unsigned f2bf_bits(float f) {
    unsigned u = __float_as_uint(f);
    return (u + 0x7fffu + ((u >> 16) & 1u)) >> 16;   // RNE
}
__device__ __forceinline__ float bf_lo(unsigned u) { return __uint_as_float(u << 16); }
__device__ __forceinline__ float bf_hi(unsigned u) { return __uint_as_float(u & 0xffff0000u); }

// ---------------- W pre-pack (all 3 layers) + zero bucket counters ----------------
// Frag (kk,ct), lane L: A[m = ct*16 + (L&15)][k = kk*32 + (L>>4)*8 + j], A = W^T.

__device__ __forceinline__ void prepack_one(const float* __restrict__ W,
                                            short* __restrict__ Wh, short* __restrict__ Wl,
                                            int DOUT, int idx) {
    int lane = idx & 63, tile = idx >> 6;
    int NT = DOUT / 16;
    int kk = tile / NT, ct = tile - kk * NT;
    int g = lane >> 4, cl = lane & 15;
    int c = ct * 16 + cl;
    short8 h8, l8;
#pragma unroll
    for (int j = 0; j < 8; ++j) {
        float w = W[(size_t)(kk * 32 + g * 8 + j) * DOUT + c];
        unsigned hb = f2bf_bits(w);
        unsigned lb = f2bf_bits(w - bf_lo(hb));
        h8[j] = (short)hb; l8[j] = (short)lb;
    }
    *reinterpret_cast<short8*>(&Wh[(size_t)idx * 8]) = h8;
    *reinterpret_cast<short8*>(&Wl[(size_t)idx * 8]) = l8;
}

__global__ __launch_bounds__(256) void prepack_all_kernel(const float* __restrict__ W1,
                                                          const float* __restrict__ W2,
                                                          const float* __restrict__ W3,
                                                          short* __restrict__ w1h, short* __restrict__ w1l,
                                                          short* __restrict__ w2h, short* __restrict__ w2l,
                                                          short* __restrict__ w3h, short* __restrict__ w3l,
                                                          int* __restrict__ bucket_cnt) {
    int idx = blockIdx.x * 256 + threadIdx.x;
    if (idx < 2048)      prepack_one(W1, w1h, w1l, 128, idx);          // 128x128: 32 tiles
    else if (idx < 3072) prepack_one(W2, w2h, w2l, 64,  idx - 2048);   // 128x64 : 16 tiles
    else if (idx < 3328) prepack_one(W3, w3h, w3l, 32,  idx - 3072);   // 64x32  :  4 tiles
    else if (idx < 3584) bucket_cnt[idx - 3328] = 0;
}

// ---------------- CSR build (bucket = 256 consecutive dst nodes) ----------------

__global__ __launch_bounds__(256) void bucket_count_kernel(const int* __restrict__ src,
                                                           const int* __restrict__ dst, int E,
                                                           int* __restrict__ bucket_cnt, int n) {
    __shared__ int bc[256];
    const int t = threadIdx.x;
    bc[t] = 0;
    __syncthreads();
    const int e0 = blockIdx.x * 4096;
#pragma unroll
    for (int k = 0; k < 16; ++k) {
        int e = e0 + k * 256 + t;
        if (e < E) {
            int dd = dst[e], ss = src[e];
            if (dd >= 0 && dd < n && ss >= 0 && ss < n) atomicAdd(&bc[dd >> 8], 1);
        }
    }
    __syncthreads();
    if (bc[t] > 0) atomicAdd(&bucket_cnt[t], bc[t]);
}

__global__ __launch_bounds__(256) void bucket_scan_kernel(const int* __restrict__ bucket_cnt, int nb,
                                                          int* __restrict__ bucket_base,
                                                          int* __restrict__ bkt_cursor,
                                                          int* __restrict__ offsets, int N) {
    __shared__ int sh[256];
    const int t = threadIdx.x;
    const int v = (t < nb) ? bucket_cnt[t] : 0;
    sh[t] = v;
    __syncthreads();
    for (int off = 1; off < 256; off <<= 1) {
        int val = (t >= off) ? sh[t - off] : 0;
        __syncthreads();
        sh[t] += val;
        __syncthreads();
    }
    if (t < nb) {
        bucket_base[t] = sh[t] - v;
        bkt_cursor[t]  = sh[t] - v;
    }
    if (t == nb - 1) { bucket_base[nb] = sh[t]; offsets[N] = sh[t]; }
}

// bin edges into bucket-major segments; entry packs (dst_local<<24 | src).
__global__ __launch_bounds__(256) void bin_kernel(const int* __restrict__ src,
                                                  const int* __restrict__ dst, int E,
                                                  int* __restrict__ bkt_cursor,
                                                  unsigned* __restrict__ bin, int n) {
    __shared__ int qcnt[256];
    __shared__ int qofs[256];
    __shared__ int gbase[256];
    __shared__ uint2 staging[4096];
    const int t = threadIdx.x;
    const int e0 = blockIdx.x * 4096;
    qcnt[t] = 0;
    __syncthreads();

    int sa[16], da[16], slot[16];
#pragma unroll
    for (int k = 0; k < 16; ++k) {
        int e = e0 + k * 256 + t;
        sa[k] = -1; da[k] = 0; slot[k] = 0;
        if (e < E) {
            int ss = src[e], dd = dst[e];
            if (ss >= 0 && ss < n && dd >= 0 && dd < n) {
                sa[k] = ss; da[k] = dd;
                slot[k] = atomicAdd(&qcnt[dd >> 8], 1);
            }
        }
    }
    __syncthreads();

    qofs[t] = qcnt[t];
    __syncthreads();
    for (int off = 1; off < 256; off <<= 1) {
        int val = (t >= off) ? qofs[t - off] : 0;
        __syncthreads();
        qofs[t] += val;
        __syncthreads();
    }
    const int tot = qofs[255];
    const int myc = qcnt[t];
    if (myc > 0) gbase[t] = atomicAdd(&bkt_cursor[t], myc);
    __syncthreads();
    qofs[t] -= qcnt[t];
    __syncthreads();

#pragma unroll
    for (int k = 0; k < 16; ++k) {
        if (sa[k] >= 0)
            staging[qofs[da[k] >> 8] + slot[k]] = make_uint2((unsigned)sa[k], (unsigned)da[k]);
    }
    __syncthreads();

    for (int i = t; i < tot; i += 256) {
        uint2 en = staging[i];
        int b = (int)(en.y >> 8);
        bin[(size_t)gbase[b] + (i - qofs[b])] = ((en.y & 255u) << 24) | en.x;
    }
}

// per-bucket: node degree count from bin + LDS scan -> offsets, dinv
__global__ __launch_bounds__(256) void node_offsets_kernel(const unsigned* __restrict__ bin,
                                                           const int* __restrict__ bucket_base,
                                                           int* __restrict__ offsets,
                                                           float* __restrict__ dinv, int n) {
    __shared__ int cnt[256];
    __shared__ int sh[256];
    const int t = threadIdx.x;
    const int b = blockIdx.x;
    cnt[t] = 0;
    __syncthreads();
    const int S = bucket_base[b], Eo = bucket_base[b + 1];
    for (int i = S + t; i < Eo; i += 256) atomicAdd(&cnt[bin[i] >> 24], 1);
    __syncthreads();
    const int c = cnt[t];
    sh[t] = c;
    __syncthreads();
    for (int off = 1; off < 256; off <<= 1) {
        int val = (t >= off) ? sh[t - off] : 0;
        __syncthreads();
        sh[t] += val;
        __syncthreads();
    }
    const int node = b * 256 + t;
    if (node < n) {
        offsets[node] = S + sh[t] - c;
        dinv[node] = rsqrtf((float)(c + 1));   // +1 self-loop
    }
}

// per-bucket fill: LDS node cursors; csr writes contiguous per block.
__global__ __launch_bounds__(256) void fill2_kernel(const int* __restrict__ offsets,
                                                    const unsigned* __restrict__ bin,
                                                    int* __restrict__ csr, int n) {
    __shared__ int cur[256];
    const int t = threadIdx.x;
    const int node0 = blockIdx.x * 256;
    if (node0 + t < n) cur[t] = offsets[node0 + t];
    __syncthreads();
    const int S  = offsets[node0];
    const int Eo = offsets[min(node0 + 256, n)];
    for (int i = S + t; i < Eo; i += 256) {
        unsigned p = bin[i];
        int pos = atomicAdd(&cur[p >> 24], 1);
        csr[pos] = (int)(p & 0xFFFFFFu);
    }
}

// ------- MFMA GEMM (split-bf16, fp32-grade): G = bf16( diag(dinv) * (X @ W) ) -------

template<int DIN, int DOUT>
__global__ __launch_bounds__(256) void mfma_gemm_kernel(const float* __restrict__ X,
                                                        const short8* __restrict__ Wp_hi,
                                                        const short8* __restrict__ Wp_lo,
                                                        const float* __restrict__ dinv,
                                                        unsigned* __restrict__ G, int n) {
    constexpr int NT  = DOUT / 16;
    constexpr int NK  = DIN / 32;
    constexpr int WPR = DIN / 2;
    __shared__ unsigned Xh[64 * WPR];
    __shared__ unsigned Xl[64 * WPR];
    const int t = threadIdx.x;
    const int row0 = blockIdx.x * 64;

    for (int i = t * 4; i < 64 * DIN; i += 1024) {
        int r = i / DIN, c = i % DIN;
        float4 v = make_float4(0.f, 0.f, 0.f, 0.f);
        if (row0 + r < n) v = *reinterpret_cast<const float4*>(&X[(size_t)(row0 + r) * DIN + c]);
        unsigned h0 = f2bf_bits(v.x), h1 = f2bf_bits(v.y), h2 = f2bf_bits(v.z), h3 = f2bf_bits(v.w);
        unsigned l0 = f2bf_bits(v.x - bf_lo(h0)), l1 = f2bf_bits(v.y - bf_lo(h1));
        unsigned l2 = f2bf_bits(v.z - bf_lo(h2)), l3 = f2bf_bits(v.w - bf_lo(h3));
        int w = (r * WPR + c / 2) ^ ((r & 7) << 2);
        *reinterpret_cast<uint2*>(&Xh[w]) = make_uint2(h0 | (h1 << 16), h2 | (h3 << 16));
        *reinterpret_cast<uint2*>(&Xl[w]) = make_uint2(l0 | (l1 << 16), l2 | (l3 << 16));
    }
    __syncthreads();

    const int lane = t & 63, wid = t >> 6;
    const int g = lane >> 4, cl = lane & 15;
    const int lrow = wid * 16 + cl;
    f32x4 acc[NT];
#pragma unroll
    for (int i = 0; i < NT; ++i) acc[i] = (f32x4){0.f, 0.f, 0.f, 0.f};

#pragma unroll
    for (int kk = 0; kk < NK; ++kk) {
        int wb = (lrow * WPR + kk * 16 + g * 4) ^ ((lrow & 7) << 2);
        short8 xh = *reinterpret_cast<const short8*>(&Xh[wb]);
        short8 xl = *reinterpret_cast<const short8*>(&Xl[wb]);
#pragma unroll
        for (int ct = 0; ct < NT; ++ct) {
            short8 wh = Wp_hi[(kk * NT + ct) * 64 + lane];
            short8 wl = Wp_lo[(kk * NT + ct) * 64 + lane];
            acc[ct] = __builtin_amdgcn_mfma_f32_16x16x32_bf16(wh, xh, acc[ct], 0, 0, 0);
            acc[ct] = __builtin_amdgcn_mfma_f32_16x16x32_bf16(wh, xl, acc[ct], 0, 0, 0);
            acc[ct] = __builtin_amdgcn_mfma_f32_16x16x32_bf16(wl, xh, acc[ct], 0, 0, 0);
        }
    }

    const int r = row0 + lrow;
    if (r < n) {
        const float s = dinv[r];
#pragma unroll
        for (int ct = 0; ct < NT; ++ct) {
            int c0 = ct * 16 + g * 4;
            unsigned p0 = f2bf_bits(acc[ct][0] * s) | (f2bf_bits(acc[ct][1] * s) << 16);
            unsigned p1 = f2bf_bits(acc[ct][2] * s) | (f2bf_bits(acc[ct][3] * s) << 16);
            *reinterpret_cast<uint2*>(&G[(size_t)r * (DOUT / 2) + c0 / 2]) = make_uint2(p0, p1);
        }
    }
}

// -------- Aggregate: out[v] = act( dinv[v] * (g[v] + sum_u g[u]) + b ), g bf16-packed --------
// uint2 loads: each lane covers 4 columns (8 B), LPN = D/4 lanes per node.

template<int D, bool RELU>
__global__ __launch_bounds__(256) void aggregate_kernel(const unsigned* __restrict__ G,
                                                        const int* __restrict__ offsets,
                                                        const int* __restrict__ csr,
                                                        const float* __restrict__ dinv,
                                                        const float* __restrict__ bias,
                                                        float* __restrict__ out, int n) {
    constexpr int W2  = D / 4;        // uint2 per row
    constexpr int LPN = W2;           // lanes per node (32/16/8)
    constexpr int NPW = 64 / LPN;     // nodes per wave
    const int lane = threadIdx.x & 63;
    const int wave = (int)((blockIdx.x * 256 + threadIdx.x) >> 6);
    const int v = wave * NPW + lane / LPN;
    if (v >= n) return;
    const int cw = lane % LPN;        // uint2 index within row
    const uint2* gB = reinterpret_cast<const uint2*>(G) + cw;

    uint2 us = gB[(size_t)v * W2];
    float a0 = bf_lo(us.x), a1 = bf_hi(us.x), a2 = bf_lo(us.y), a3 = bf_hi(us.y);
    float b0 = 0.f, b1 = 0.f, b2 = 0.f, b3 = 0.f;
    float c0 = 0.f, c1 = 0.f, c2 = 0.f, c3 = 0.f;
    float d0 = 0.f, d1 = 0.f, d2 = 0.f, d3 = 0.f;

    const int s = offsets[v], e = offsets[v + 1];
    int j = s;
    for (; j + 4 <= e; j += 4) {
        uint2 u0 = gB[(size_t)csr[j]     * W2];
        uint2 u1 = gB[(size_t)csr[j + 1] * W2];
        uint2 u2 = gB[(size_t)csr[j + 2] * W2];
        uint2 u3 = gB[(size_t)csr[j + 3] * W2];
        a0 += bf_lo(u0.x); a1 += bf_hi(u0.x); a2 += bf_lo(u0.y); a3 += bf_hi(u0.y);
        b0 += bf_lo(u1.x); b1 += bf_hi(u1.x); b2 += bf_lo(u1.y); b3 += bf_hi(u1.y);
        c0 += bf_lo(u2.x); c1 += bf_hi(u2.x); c2 += bf_lo(u2.y); c3 += bf_hi(u2.y);
        d0 += bf_lo(u3.x); d1 += bf_hi(u3.x); d2 += bf_lo(u3.y); d3 += bf_hi(u3.y);
    }
    for (; j < e; ++j) {
        uint2 u0 = gB[(size_t)csr[j] * W2];
        a0 += bf_lo(u0.x); a1 += bf_hi(u0.x); a2 += bf_lo(u0.y); a3 += bf_hi(u0.y);
    }
    a0 += b0 + c0 + d0;  a1 += b1 + c1 + d1;
    a2 += b2 + c2 + d2;  a3 += b3 + c3 + d3;

    const float dv = dinv[v];
    const int col = cw * 4;
    float4 bs = *reinterpret_cast<const float4*>(&bias[col]);
    float4 o = make_float4(dv * a0 + bs.x, dv * a1 + bs.y, dv * a2 + bs.z, dv * a3 + bs.w);
    if (RELU) {
        o.x = fmaxf(o.x, 0.f); o.y = fmaxf(o.y, 0.f);
        o.z = fmaxf(o.z, 0.f); o.w = fmaxf(o.w, 0.f);
    }
    *reinterpret_cast<float4*>(&out[(size_t)v * D + col]) = o;
}

// ---------------- launch ----------------

extern "C" void kernel_launch(void* const* d_in, const int* in_sizes, int n_in,
                              void* d_out, int out_size, void* d_ws, size_t ws_size,
                              hipStream_t stream) {
    const int N = 50000, E = 800000;
    const int NB  = (N + 255) / 256;     // 196 buckets
    const int NBE = (E + 4095) / 4096;   // 196 edge blocks
    const int NG  = (N + 63) / 64;
    const float* x  = (const float*)d_in[0];
    const int* ei = (const int*)d_in[1];
    const int* src = ei;
    const int* dst = ei + E;
    const float* W1 = (const float*)d_in[2]; const float* b1 = (const float*)d_in[3];
    const float* W2 = (const float*)d_in[4]; const float* b2 = (const float*)d_in[5];
    const float* W3 = (const float*)d_in[6]; const float* b3 = (const float*)d_in[7];
    float* out = (float*)d_out;

    char* ws = (char*)d_ws;
    size_t off = 0;
    auto alloc = [&](size_t bytes) -> void* {
        void* p = ws + off;
        off = (off + bytes + 255) & ~(size_t)255;
        return p;
    };
    int*      offsets     = (int*)alloc((size_t)(N + 1) * 4);
    float*    dinv        = (float*)alloc((size_t)N * 4);
    int*      csr         = (int*)alloc((size_t)E * 4);
    unsigned* g           = (unsigned*)alloc((size_t)N * 64 * 4);
    float*    h           = (float*)alloc((size_t)N * 128 * 4);
    int*      bucket_cnt  = (int*)alloc((size_t)256 * 4);
    int*      bucket_base = (int*)alloc((size_t)257 * 4);
    int*      bkt_cursor  = (int*)alloc((size_t)256 * 4);
    short*    wp1h = (short*)alloc((size_t)128 * 128 * 2);
    short*    wp1l = (short*)alloc((size_t)128 * 128 * 2);
    short*    wp2h = (short*)alloc((size_t)128 * 64 * 2);
    short*    wp2l = (short*)alloc((size_t)128 * 64 * 2);
    short*    wp3h = (short*)alloc((size_t)64 * 32 * 2);
    short*    wp3l = (short*)alloc((size_t)64 * 32 * 2);
    unsigned* bin         = (unsigned*)h;  // alias: consumed before h is written
    (void)ws_size; (void)n_in; (void)in_sizes; (void)out_size;

    // prepack W (all layers) + zero bucket counters
    prepack_all_kernel<<<14, 256, 0, stream>>>(W1, W2, W3, wp1h, wp1l, wp2h, wp2l, wp3h, wp3l,
                                               bucket_cnt);

    // CSR build
    bucket_count_kernel<<<NBE, 256, 0, stream>>>(src, dst, E, bucket_cnt, N);
    bucket_scan_kernel<<<1, 256, 0, stream>>>(bucket_cnt, NB, bucket_base, bkt_cursor, offsets, N);
    bin_kernel<<<NBE, 256, 0, stream>>>(src, dst, E, bkt_cursor, bin, N);
    node_offsets_kernel<<<NB, 256, 0, stream>>>(bin, bucket_base, offsets, dinv, N);
    fill2_kernel<<<NB, 256, 0, stream>>>(offsets, bin, csr, N);

    // layer 1: 128 -> 128, relu
    mfma_gemm_kernel<128, 128><<<NG, 256, 0, stream>>>(x, (const short8*)wp1h, (const short8*)wp1l, dinv, g, N);
    aggregate_kernel<128, true><<<(N + 7) / 8, 256, 0, stream>>>(g, offsets, csr, dinv, b1, h, N);
    // layer 2: 128 -> 64, relu
    mfma_gemm_kernel<128, 64><<<NG, 256, 0, stream>>>(h, (const short8*)wp2h, (const short8*)wp2l, dinv, g, N);
    aggregate_kernel<64, true><<<(N + 15) / 16, 256, 0, stream>>>(g, offsets, csr, dinv, b2, h, N);
    // layer 3: 64 -> 32, no relu -> d_out
    mfma_gemm_kernel<64, 32><<<NG, 256, 0, stream>>>(h, (const short8*)wp3h, (const short8*)wp3l, dinv, g, N);
    aggregate_kernel<32, false><<<(N + 31) / 32, 256, 0, stream>>>(g, offsets, csr, dinv, b3, out, N);
}